// Round 15
// baseline (320.843 us; speedup 1.0000x reference)
//
#include <hip/hip_runtime.h>
#include <hip/hip_cooperative_groups.h>
#include <stdint.h>

namespace cg = cooperative_groups;

// Match numpy semantics: no FMA contraction anywhere in decision-critical math.
#pragma clang fp contract(off)

#define N_ANCHORS 172032  // compile-time problem constant
#define MAX_OUT 200
#define KTOP 2048         // top-K prefix capacity
#define NCHUNK (KTOP / 64)
#define BLK 1024
#define GRID 168          // GRID*BLK == N_ANCHORS exactly
#define NW (BLK / 64)
#define SEG 32            // per-block segment capacity (lambda~9.6, P(>32)~1e-9; guarded)
#define VT 2.35f          // fixed prefix threshold: scores ~ N(0,1) =>
                          // csel ~ 1615 +/- 40 (5sig < 2048); rank_200 < 900
                          // (round-5 evidence). Exact fallback guards everything.

typedef unsigned long long ull;
static_assert(GRID * BLK == N_ANCHORS, "grid covers anchors exactly");

// f64 decode: f32 inputs upcast to f64, reference op order. Returns (y1,x1,y2,x2).
__device__ __forceinline__ void decode_box_d(const float4* __restrict__ reg,
                                             const float4* __restrict__ anc, int i,
                                             double b[4]) {
#pragma clang fp contract(off)
    float4 r = reg[i];
    float4 a = anc[i];
    double dx = (double)r.x * 0.1;
    double dy = (double)r.y * 0.1;
    double dw = (double)r.z * 0.2;
    double dh = (double)r.w * 0.2;
    double xa = (double)a.x, ya = (double)a.y, wa = (double)a.z, ha = (double)a.w;
    double xc = dx * wa; xc = xc + xa;     // dx*w_a + x_a
    double yc = dy * ha; yc = yc + ya;     // dy*h_a + y_a
    double w = exp(dw) * wa;
    double h = exp(dh) * ha;
    double h2 = h * 0.5, w2 = w * 0.5;
    b[0] = yc - h2; b[1] = xc - w2; b[2] = yc + h2; b[3] = xc + w2;
}

// Gather + f64 decode one output row (boxes + landmarks), write f32.
__device__ __forceinline__ void write_row(const float4* __restrict__ reg,
                                          const float4* __restrict__ anc,
                                          const float* __restrict__ lnd,
                                          int q, int idx, float* __restrict__ out) {
#pragma clang fp contract(off)
    float b[4] = {0.f, 0.f, 0.f, 0.f};
    float l10[10] = {0.f, 0.f, 0.f, 0.f, 0.f, 0.f, 0.f, 0.f, 0.f, 0.f};
    if (idx >= 0) {
        double bb[4];
        decode_box_d(reg, anc, idx, bb);
        b[0] = (float)bb[0]; b[1] = (float)bb[1]; b[2] = (float)bb[2]; b[3] = (float)bb[3];
        float4 a = anc[idx];
        double xa = (double)a.x, ya = (double)a.y, wa = (double)a.z, ha = (double)a.w;
        for (int j = 0; j < 5; ++j) {
            double lx = (double)lnd[idx * 10 + 2 * j]     * 0.1;
            double ly = (double)lnd[idx * 10 + 2 * j + 1] * 0.1;
            lx = lx * wa; lx = lx + xa;
            ly = ly * ha; ly = ly + ya;
            l10[2 * j] = (float)lx; l10[2 * j + 1] = (float)ly;
        }
    }
    for (int c = 0; c < 4; ++c)  out[q * 4 + c] = b[c];
    for (int c = 0; c < 10; ++c) out[MAX_OUT * 4 + q * 10 + c] = l10[c];
}

__device__ __forceinline__ ull wmax(ull k) {
    for (int d = 32; d > 0; d >>= 1) {
        ull o = __shfl_down(k, d, 64);
        if (o > k) k = o;
    }
    return k;
}

// ---------- cooperative kernel: compact -> rank -> mat -> scan -> output ----------
__global__ void __launch_bounds__(BLK)
k_all(const float2* __restrict__ cls, const float4* __restrict__ reg,
      const float4* __restrict__ anc, const float* __restrict__ lnd,
      int* __restrict__ segcnt, ull* __restrict__ segkeys,
      int* __restrict__ g_meta, int* __restrict__ sidx_g,
      float4* __restrict__ sbox_g, ull* __restrict__ mat,
      int* __restrict__ flag, float* __restrict__ out) {
    cg::grid_group gg = cg::this_grid();
    __shared__ ull sk[KTOP];             // 16 KB (phase B)
    __shared__ int scnt[GRID];
    __shared__ int spre[GRID + 1];
    __shared__ int wcnt[NW];
    __shared__ unsigned int s_rm[64];    // removed mask, 32 ranks/word (phase D)
    __shared__ int s_kept[MAX_OUT];
    __shared__ int s_prk[64];
    __shared__ int s_np, s_ln, s_ok, s_csel;

    const int tid = threadIdx.x;
    const int bid = blockIdx.x;

    // ---- phase A: per-block candidate compaction into fixed segments ----
    {
        int i = bid * BLK + tid;
        float sc = cls[i].y;             // score = cls[:,1]
        bool c = (sc > VT);
        ull key = 0ull;
        if (c) key = ((ull)__float_as_uint(sc) << 32)
                   | (ull)(0xFFFFFFFFu - (unsigned int)i);
        ull m = __ballot(c);
        int wid = tid >> 6, lane = tid & 63;
        if (lane == 0) wcnt[wid] = __popcll(m);
        __syncthreads();
        if (tid == 0) {
            int s = 0;
            for (int w = 0; w < NW; ++w) { int t = wcnt[w]; wcnt[w] = s; s += t; }
            segcnt[bid] = s;             // unconditional: no memset needed
        }
        __syncthreads();
        if (c) {
            int pos = wcnt[wid] + __popcll(m & ((1ull << lane) - 1ull));
            if (pos < SEG) segkeys[bid * SEG + pos] = key;
        }
    }
    __threadfence();
    gg.sync();

    // ---- phase B: block 0 — gather segments, rank-by-count, decode to rank order ----
    if (bid == 0) {
        for (int s = tid; s < GRID; s += BLK) scnt[s] = segcnt[s];
        __syncthreads();
        if (tid == 0) {
            int acc = 0, ok = 1;
            for (int s = 0; s < GRID; ++s) {
                spre[s] = acc;
                if (scnt[s] > SEG) ok = 0;
                acc += scnt[s];
            }
            if (acc > KTOP) ok = 0;
            s_ok = ok; s_csel = acc;
            g_meta[0] = acc; g_meta[1] = ok;
        }
        __syncthreads();
        if (s_ok) {
            int csel = s_csel;
            // parallel gather: task t -> (segment, slot)
            for (int t = tid; t < GRID * SEG; t += BLK) {
                int s = t / SEG, k = t % SEG;
                if (k < scnt[s]) sk[spre[s] + k] = segkeys[s * SEG + k];
            }
            for (int j = csel + tid; j < KTOP; j += BLK) sk[j] = 0ull;
            __syncthreads();
            // rank-by-count (keys unique; round-13-validated)
            ull my0 = sk[tid], my1 = sk[tid + BLK];
            int r0 = 0, r1 = 0;
            for (int j = 0; j < KTOP; ++j) {
                ull k = sk[j];           // broadcast read
                r0 += (k > my0) ? 1 : 0;
                r1 += (k > my1) ? 1 : 0;
            }
            if (my0 != 0ull) {
                int idx = (int)(0xFFFFFFFFu - (unsigned int)my0);
                double b[4]; decode_box_d(reg, anc, idx, b);
                sbox_g[r0] = make_float4((float)b[0], (float)b[1], (float)b[2], (float)b[3]);
                sidx_g[r0] = idx;
            }
            if (my1 != 0ull) {
                int idx = (int)(0xFFFFFFFFu - (unsigned int)my1);
                double b[4]; decode_box_d(reg, anc, idx, b);
                sbox_g[r1] = make_float4((float)b[0], (float)b[1], (float)b[2], (float)b[3]);
                sidx_g[r1] = idx;
            }
            for (int r = csel + tid; r < KTOP; r += BLK) {
                sbox_g[r] = make_float4(0.f, 0.f, 0.f, 0.f);  // zero-area: IoU = 0
                sidx_g[r] = -1;
            }
        }
    }
    __threadfence();
    gg.sync();

    // ---- phase C: all blocks — suppression bit-matrix (round-11 semantics) ----
    {
        int ok = g_meta[1], csel = g_meta[0];
        int q = bid * BLK + tid;
        if (ok && q < KTOP * 32) {
            int i = q >> 5, w = q & 31;
            if (i < csel && w >= (i >> 6)) {
                float4 bi = sbox_g[i];
                double q0 = (double)bi.x, q1 = (double)bi.y;
                double q2 = (double)bi.z, q3 = (double)bi.w;
                double ai = (q2 - q0) * (q3 - q1);
                ull bits = 0;
                int j0 = w << 6;
                for (int b = 0; b < 64; ++b) {
                    int j = j0 + b;
                    if (j > i) {
                        float4 bj = sbox_g[j];
                        double y1 = (double)bj.x, x1 = (double)bj.y;
                        double y2 = (double)bj.z, x2 = (double)bj.w;
                        double ih = fmin(y2, q2) - fmax(y1, q0); ih = fmax(ih, 0.0);
                        double iw = fmin(x2, q3) - fmax(x1, q1); iw = fmax(iw, 0.0);
                        double inter = ih * iw;
                        double aj = (y2 - y1) * (x2 - x1);
                        double den = aj + ai; den = den - inter; den = den + 1e-12;
                        if (inter / den > 0.4) bits |= (1ull << b);
                    }
                }
                mat[(size_t)i * 32 + w] = bits;
            }
        }
    }
    __threadfence();
    gg.sync();

    // ---- phase D: block 0 — chunked scan over mat + fused output ----
    if (bid == 0) {
        int ok = g_meta[1], csel = g_meta[0];
        if (tid == 0) s_ln = 0;
        if (tid < 64) {
            int rb = tid << 5;
            unsigned int m = 0u;
            if (rb >= csel) m = 0xFFFFFFFFu;
            else if (rb + 32 > csel) m = ~((1u << (csel - rb)) - 1u);
            s_rm[tid] = m;
        }
        __syncthreads();
        if (ok) {
            for (int c = 0; c < NCHUNK; ++c) {
                int base = c << 6;
                if (base >= csel) break;            // uniform
                if (s_ln >= MAX_OUT) break;         // uniform (post-barrier read)
                // wave 0: prefetch diag word + sidx for this chunk, then scan
                if (tid < 64) {
                    ull diag = mat[(size_t)(base + tid) * 32 + c];
                    int sidx_l = sidx_g[base + tid];
                    ull cur = ((ull)s_rm[2 * c]) | (((ull)s_rm[2 * c + 1]) << 32);
                    ull avail = ~cur;               // uniform across wave
                    int ln = s_ln, np = 0;
                    while (avail != 0ull && ln < MAX_OUT) {
                        int b = __ffsll(avail) - 1;
                        int sv = __shfl(sidx_l, b);
                        ull rowb = __shfl(diag, b); // row b's in-chunk bits (j>b)
                        if (tid == 0) { s_kept[ln] = sv; s_prk[np] = base + b; }
                        ln++; np++;
                        avail &= ~rowb;
                        avail &= ~(1ull << b);      // pick removes itself
                    }
                    if (tid == 0) { s_ln = ln; s_np = np; }
                }
                __syncthreads();
                // all threads: batch-OR the chunk's pick rows into s_rm (words >= c)
                int np = s_np;
                for (int t = tid; t < np * 32; t += BLK) {
                    int p = t >> 5, w = t & 31;
                    if (w >= c) {                   // words < c unwritten in mat; never needed
                        ull bits = mat[(size_t)s_prk[p] * 32 + w];
                        if (bits) {
                            unsigned int lo = (unsigned int)bits;
                            unsigned int hi = (unsigned int)(bits >> 32);
                            if (lo) atomicOr(&s_rm[2 * w], lo);
                            if (hi) atomicOr(&s_rm[2 * w + 1], hi);
                        }
                    }
                }
                __syncthreads();
            }
        }
        int ln = s_ln;
        bool good = ok && (ln >= MAX_OUT);
        if (tid == 0) *flag = good ? 0 : 1;         // unconditional flag write
        if (good && tid < MAX_OUT) write_row(reg, anc, lnd, tid, s_kept[tid], out);
    }
}

// ---------- exact self-contained fallback (flag-gated; never runs on this data) ----------
__global__ void __launch_bounds__(BLK) k_slow(const float2* __restrict__ cls,
                                              const float4* __restrict__ reg,
                                              const float4* __restrict__ anc,
                                              const float* __restrict__ lnd, int n,
                                              const int* __restrict__ flag,
                                              float* __restrict__ sbuf,
                                              float* __restrict__ out) {
    if (*flag == 0) return;              // expected path: exit immediately
    __shared__ ull warr[NW];
    __shared__ ull s_win;
    __shared__ double s_pb[5];
    __shared__ int kidx[MAX_OUT];
    int tid = threadIdx.x;
    for (int i = tid; i < n; i += BLK) {
        float sc = cls[i].y;
        sbuf[i] = ((double)sc > 0.4) ? sc : 0.0f;
    }
    __syncthreads();
    int ln = 0;
    for (int oi = 0; oi < MAX_OUT; ++oi) {
        ull k = 0;
        for (int i = tid; i < n; i += BLK) {
            ull kk = ((ull)__float_as_uint(sbuf[i]) << 32)
                   | (ull)(0xFFFFFFFFu - (unsigned int)i);
            if (kk > k) k = kk;
        }
        k = wmax(k);
        if ((tid & 63) == 0) warr[tid >> 6] = k;
        __syncthreads();
        if (tid < 64) {
            ull v = (tid < NW) ? warr[tid] : 0ull;
            v = wmax(v);
            if (tid == 0) s_win = v;
        }
        __syncthreads();
        ull win = s_win;
        if ((win >> 32) == 0u) break;
        int pidx = (int)(0xFFFFFFFFu - (unsigned int)win);
        if (tid == 0) {
            double b[4];
            decode_box_d(reg, anc, pidx, b);
            s_pb[0] = b[0]; s_pb[1] = b[1]; s_pb[2] = b[2]; s_pb[3] = b[3];
            s_pb[4] = (b[2] - b[0]) * (b[3] - b[1]);
            kidx[oi] = pidx;
        }
        __syncthreads();
        double p0 = s_pb[0], p1 = s_pb[1], p2 = s_pb[2], p3 = s_pb[3], pa = s_pb[4];
        for (int i = tid; i < n; i += BLK) {
            float v = sbuf[i];
            if (v != 0.0f) {
                double b[4];
                decode_box_d(reg, anc, i, b);
                double ih = fmin(b[2], p2) - fmax(b[0], p0); ih = fmax(ih, 0.0);
                double iw = fmin(b[3], p3) - fmax(b[1], p1); iw = fmax(iw, 0.0);
                double inter = ih * iw;
                double aa = (b[2] - b[0]) * (b[3] - b[1]);
                double den = aa + pa; den = den - inter; den = den + 1e-12;
                if (inter / den > 0.4) sbuf[i] = 0.0f;   // kills the pick too
            }
        }
        __syncthreads();
        ln = oi + 1;
    }
    __syncthreads();
    if (tid < MAX_OUT)
        write_row(reg, anc, lnd, tid, (tid < ln) ? kidx[tid] : -1, out);
}

extern "C" void kernel_launch(void* const* d_in, const int* in_sizes, int n_in,
                              void* d_out, int out_size, void* d_ws, size_t ws_size,
                              hipStream_t stream) {
    const float2* cls = (const float2*)d_in[0];    // (N,2) f32
    const float4* reg = (const float4*)d_in[1];    // (N,4) f32
    const float*  lnd = (const float*)d_in[2];     // (N,10) f32
    const float4* anc = (const float4*)d_in[3];    // (N,4) f32
    int n = N_ANCHORS;
    float* outp = (float*)d_out;

    uint8_t* w = (uint8_t*)d_ws;
    int*    segcnt  = (int*)w;                  //      0: 672 B (pad to 1024)
    ull*    segkeys = (ull*)(w + 1024);         //   1024: 168*32*8 = 43008 B
    int*    g_meta  = (int*)(w + 44032);        //  44032: 64 B
    int*    flag    = (int*)(w + 44096);        //  44096: 64 B
    int*    sidx_g  = (int*)(w + 44160);        //  44160: 8192 B
    float4* sbox_g  = (float4*)(w + 52352);     //  52352: 32768 B
    ull*    mat     = (ull*)(w + 85120);        //  85120: 524288 B
    float*  sbuf    = (float*)(w + 609408);     // 609408: N*4 B (fallback only)

    void* args[] = { (void*)&cls, (void*)&reg, (void*)&anc, (void*)&lnd,
                     (void*)&segcnt, (void*)&segkeys, (void*)&g_meta,
                     (void*)&sidx_g, (void*)&sbox_g, (void*)&mat,
                     (void*)&flag, (void*)&outp };
    hipLaunchCooperativeKernel((const void*)k_all, dim3(GRID), dim3(BLK),
                               args, 0, stream);
    k_slow<<<1, BLK, 0, stream>>>(cls, reg, anc, lnd, n, flag, sbuf, outp);
}

// Round 16
// 140.427 us; speedup vs baseline: 2.2848x; 2.2848x over previous
//
#include <hip/hip_runtime.h>
#include <stdint.h>

// Match numpy semantics: no FMA contraction anywhere in decision-critical math.
#pragma clang fp contract(off)

#define N_ANCHORS 172032  // compile-time problem constant
#define MAX_OUT 200
#define KTOP 2048         // top-K prefix capacity
#define NCHUNK (KTOP / 64)
#define BLK 1024
#define GRID 168          // GRID*BLK == N_ANCHORS exactly
#define NW (BLK / 64)
#define SEG 32            // per-block segment capacity (lambda~9.6, P(>32)~1e-9; guarded)
#define VT 2.35f          // fixed prefix threshold: scores ~ N(0,1) =>
                          // csel ~ 1615 +/- 40 (5sig < 2048); rank_200 < 900
                          // (round-5 evidence). Inline exact fallback guards all.

typedef unsigned long long ull;
static_assert(GRID * BLK == N_ANCHORS, "grid covers anchors exactly");

// f64 decode: f32 inputs upcast to f64, reference op order. Returns (y1,x1,y2,x2).
__device__ __forceinline__ void decode_box_d(const float4* __restrict__ reg,
                                             const float4* __restrict__ anc, int i,
                                             double b[4]) {
#pragma clang fp contract(off)
    float4 r = reg[i];
    float4 a = anc[i];
    double dx = (double)r.x * 0.1;
    double dy = (double)r.y * 0.1;
    double dw = (double)r.z * 0.2;
    double dh = (double)r.w * 0.2;
    double xa = (double)a.x, ya = (double)a.y, wa = (double)a.z, ha = (double)a.w;
    double xc = dx * wa; xc = xc + xa;     // dx*w_a + x_a
    double yc = dy * ha; yc = yc + ya;     // dy*h_a + y_a
    double w = exp(dw) * wa;
    double h = exp(dh) * ha;
    double h2 = h * 0.5, w2 = w * 0.5;
    b[0] = yc - h2; b[1] = xc - w2; b[2] = yc + h2; b[3] = xc + w2;
}

// Gather + f64 decode one output row (boxes + landmarks), write f32.
__device__ __forceinline__ void write_row(const float4* __restrict__ reg,
                                          const float4* __restrict__ anc,
                                          const float* __restrict__ lnd,
                                          int q, int idx, float* __restrict__ out) {
#pragma clang fp contract(off)
    float b[4] = {0.f, 0.f, 0.f, 0.f};
    float l10[10] = {0.f, 0.f, 0.f, 0.f, 0.f, 0.f, 0.f, 0.f, 0.f, 0.f};
    if (idx >= 0) {
        double bb[4];
        decode_box_d(reg, anc, idx, bb);
        b[0] = (float)bb[0]; b[1] = (float)bb[1]; b[2] = (float)bb[2]; b[3] = (float)bb[3];
        float4 a = anc[idx];
        double xa = (double)a.x, ya = (double)a.y, wa = (double)a.z, ha = (double)a.w;
        for (int j = 0; j < 5; ++j) {
            double lx = (double)lnd[idx * 10 + 2 * j]     * 0.1;
            double ly = (double)lnd[idx * 10 + 2 * j + 1] * 0.1;
            lx = lx * wa; lx = lx + xa;
            ly = ly * ha; ly = ly + ya;
            l10[2 * j] = (float)lx; l10[2 * j + 1] = (float)ly;
        }
    }
    for (int c = 0; c < 4; ++c)  out[q * 4 + c] = b[c];
    for (int c = 0; c < 10; ++c) out[MAX_OUT * 4 + q * 10 + c] = l10[c];
}

__device__ __forceinline__ ull wmax(ull k) {
    for (int d = 32; d > 0; d >>= 1) {
        ull o = __shfl_down(k, d, 64);
        if (o > k) k = o;
    }
    return k;
}

// f64 IoU > 0.4 test, reference op order.
__device__ __forceinline__ bool iou_gt_f4(float4 a, float4 p) {
#pragma clang fp contract(off)
    double y1 = (double)a.x, x1 = (double)a.y, y2 = (double)a.z, x2 = (double)a.w;
    double p0 = (double)p.x, p1 = (double)p.y, p2 = (double)p.z, p3 = (double)p.w;
    double ih = fmin(y2, p2) - fmax(y1, p0); ih = fmax(ih, 0.0);
    double iw = fmin(x2, p3) - fmax(x1, p1); iw = fmax(iw, 0.0);
    double inter = ih * iw;
    double aj = (y2 - y1) * (x2 - x1);
    double ap = (p2 - p0) * (p3 - p1);
    double den = aj + ap; den = den - inter; den = den + 1e-12;
    return (inter / den) > 0.4;
}

// ---------- kernel 1: segment compaction (no atomics, no memset needed) ----------
__global__ void __launch_bounds__(BLK) k_seg(const float2* __restrict__ cls,
                                             int* __restrict__ segcnt,
                                             ull* __restrict__ segkeys) {
    __shared__ int wcnt[NW];
    int tid = threadIdx.x, bid = blockIdx.x;
    int i = bid * BLK + tid;
    float sc = cls[i].y;                   // score = cls[:,1]
    bool c = (sc > VT);
    ull key = 0ull;
    if (c) key = ((ull)__float_as_uint(sc) << 32)
               | (ull)(0xFFFFFFFFu - (unsigned int)i);
    ull m = __ballot(c);
    int wid = tid >> 6, lane = tid & 63;
    if (lane == 0) wcnt[wid] = __popcll(m);
    __syncthreads();
    if (tid == 0) {
        int s = 0;
        for (int w = 0; w < NW; ++w) { int t = wcnt[w]; wcnt[w] = s; s += t; }
        segcnt[bid] = s;                   // unconditional (overflow detected downstream)
    }
    __syncthreads();
    if (c) {
        int pos = wcnt[wid] + __popcll(m & ((1ull << lane) - 1ull));
        if (pos < SEG) segkeys[bid * SEG + pos] = key;
    }
}

// ---------- kernel 2: gather + sort + lazy/diag greedy + output (+inline fallback) ----------
__global__ void __launch_bounds__(BLK) k_fused(const float2* __restrict__ cls,
                                               const float4* __restrict__ reg,
                                               const float4* __restrict__ anc,
                                               const float* __restrict__ lnd,
                                               const int* __restrict__ segcnt,
                                               const ull* __restrict__ segkeys,
                                               float* __restrict__ sbuf,
                                               float* __restrict__ out) {
    __shared__ ull sk[KTOP];             // 16 KB
    __shared__ float4 sbox[KTOP];        // 32 KB (rank order)
    __shared__ int ssidx[KTOP];          // 8 KB  (rank order)
    __shared__ float4 s_pbox[MAX_OUT];   // 3.2 KB (picked boxes so far)
    __shared__ unsigned int dmat[128];   // 64x64 diag suppression block
    __shared__ unsigned int s_lz[2];     // lazy-removed mask for current chunk
    __shared__ int s_kept[MAX_OUT];
    __shared__ int s_prk[64];
    __shared__ int scnt[GRID];
    __shared__ int spre[GRID];
    __shared__ int s_ln, s_np, s_ok, s_csel;
    __shared__ ull warr[NW];             // fallback
    __shared__ ull s_win;
    __shared__ double s_pb[5];

    int tid = threadIdx.x;

    // ---- phase 0: gather segments, compute csel ----
    for (int s = tid; s < GRID; s += BLK) scnt[s] = segcnt[s];
    __syncthreads();
    if (tid == 0) {
        int acc = 0, ok = 1;
        for (int s = 0; s < GRID; ++s) {
            spre[s] = acc;
            if (scnt[s] > SEG) ok = 0;
            acc += scnt[s];
        }
        if (acc > KTOP) ok = 0;
        s_ok = ok; s_csel = acc; s_ln = 0;
    }
    __syncthreads();
    bool pre_ok = (s_ok != 0);
    int csel = s_csel;
    int ln = 0;

    if (pre_ok) {
        for (int t = tid; t < GRID * SEG; t += BLK) {
            int s = t / SEG, k = t % SEG;
            if (k < scnt[s]) sk[spre[s] + k] = segkeys[s * SEG + k];
        }
        for (int j = csel + tid; j < KTOP; j += BLK) sk[j] = 0ull;
        __syncthreads();

        // bitonic sort desc (score desc, idx asc via ~idx) — validated r2/11/12/14
        for (int k = 2; k <= KTOP; k <<= 1) {
            for (int j = k >> 1; j > 0; j >>= 1) {
                for (int i = tid; i < KTOP; i += BLK) {
                    int l = i ^ j;
                    if (l > i) {
                        bool desc = ((i & k) == 0);
                        ull a = sk[i], b = sk[l];
                        if (desc ? (a < b) : (a > b)) { sk[i] = b; sk[l] = a; }
                    }
                }
                __syncthreads();
            }
        }

        // decode boxes into rank order
        for (int r = tid; r < KTOP; r += BLK) {
            if (r < csel) {
                int idx = (int)(0xFFFFFFFFu - (unsigned int)sk[r]);
                ssidx[r] = idx;
                double b[4];
                decode_box_d(reg, anc, idx, b);
                sbox[r] = make_float4((float)b[0], (float)b[1], (float)b[2], (float)b[3]);
            } else {
                ssidx[r] = -1;
                sbox[r] = make_float4(0.f, 0.f, 0.f, 0.f);
            }
        }
        __syncthreads();

        // ---- chunked greedy: lazy pick-check + diag scan (barriers: 4/chunk) ----
        for (int c = 0; c < NCHUNK; ++c) {
            int base = c << 6;
            if (base >= csel) break;                    // uniform
            if (tid < 128) dmat[tid] = 0u;
            if (tid < 2) s_lz[tid] = 0u;
            __syncthreads();
            int npt = s_ln;                             // picks so far (uniform)
            // lazy: test this chunk's 64 ranks vs all prior picks (16 thr/rank)
            {
                int rr = tid >> 4, sub = tid & 15;
                int r = base + rr;
                bool dead = false;
                if (r < csel && npt > 0) {
                    float4 bj = sbox[r];
                    for (int p = sub; p < npt; p += 16) {
                        if (iou_gt_f4(bj, s_pbox[p])) { dead = true; break; }
                    }
                }
                if (dead) atomicOr(&s_lz[rr >> 5], 1u << (rr & 31));
            }
            // diag 64x64 block (validated r14): thread t -> row=t>>4, 4 cols
            {
                int row = tid >> 4, cg = tid & 15;
                float4 bi = sbox[base + row];
                unsigned int bits = 0;
                for (int e = 0; e < 4; ++e) {
                    int col = (cg << 2) + e;
                    if (col > row && iou_gt_f4(sbox[base + col], bi))
                        bits |= 1u << (col & 31);
                }
                if (bits) atomicOr(&dmat[(row << 1) + (cg >> 3)], bits);
            }
            __syncthreads();
            // wave-0 scan: diag rows per-lane, fetch via shfl (validated r14)
            if (tid < 64) {
                ull lz = ((ull)s_lz[0]) | (((ull)s_lz[1]) << 32);
                int rem = csel - base;
                ull valid = (rem >= 64) ? ~0ull : ((1ull << rem) - 1ull);
                ull avail = ~lz & valid;
                ull myrow = ((ull)dmat[tid << 1]) | (((ull)dmat[(tid << 1) + 1]) << 32);
                int sidx_l = ssidx[base + tid];
                int lnl = s_ln, np = 0;
                while (avail != 0ull && lnl < MAX_OUT) {
                    int b = __ffsll(avail) - 1;
                    int sv = __shfl(sidx_l, b);
                    ull rowb = __shfl(myrow, b);
                    if (tid == 0) { s_kept[lnl] = sv; s_prk[np] = base + b; }
                    lnl++; np++;
                    avail &= ~rowb;
                    avail &= ~(1ull << b);              // pick removes itself
                }
                if (tid == 0) { s_ln = lnl; s_np = np; }
            }
            __syncthreads();
            // append this chunk's pick boxes to s_pbox
            {
                int np = s_np, l2 = s_ln;
                if (tid < np) s_pbox[l2 - np + tid] = sbox[s_prk[tid]];
            }
            __syncthreads();
            if (s_ln >= MAX_OUT) break;                 // uniform post-barrier
        }
        ln = s_ln;
    }

    bool need = (!pre_ok) || (ln < MAX_OUT);            // uniform
    if (!need) {
        if (tid < MAX_OUT) write_row(reg, anc, lnd, tid, s_kept[tid], out);
        return;
    }

    // ---- inline exact fallback: literal greedy over all N (round-10 validated) ----
    for (int i = tid; i < N_ANCHORS; i += BLK) {
        float sc = cls[i].y;
        sbuf[i] = ((double)sc > 0.4) ? sc : 0.0f;
    }
    __syncthreads();
    ln = 0;
    for (int oi = 0; oi < MAX_OUT; ++oi) {
        ull k = 0;
        for (int i = tid; i < N_ANCHORS; i += BLK) {
            ull kk = ((ull)__float_as_uint(sbuf[i]) << 32)
                   | (ull)(0xFFFFFFFFu - (unsigned int)i);
            if (kk > k) k = kk;
        }
        k = wmax(k);
        if ((tid & 63) == 0) warr[tid >> 6] = k;
        __syncthreads();
        if (tid < 64) {
            ull v = (tid < NW) ? warr[tid] : 0ull;
            v = wmax(v);
            if (tid == 0) s_win = v;
        }
        __syncthreads();
        ull win = s_win;
        if ((win >> 32) == 0u) break;
        int pidx = (int)(0xFFFFFFFFu - (unsigned int)win);
        if (tid == 0) {
            double b[4];
            decode_box_d(reg, anc, pidx, b);
            s_pb[0] = b[0]; s_pb[1] = b[1]; s_pb[2] = b[2]; s_pb[3] = b[3];
            s_pb[4] = (b[2] - b[0]) * (b[3] - b[1]);
            s_kept[oi] = pidx;
        }
        __syncthreads();
        double p0 = s_pb[0], p1 = s_pb[1], p2 = s_pb[2], p3 = s_pb[3], pa = s_pb[4];
        for (int i = tid; i < N_ANCHORS; i += BLK) {
            float v = sbuf[i];
            if (v != 0.0f) {
                double b[4];
                decode_box_d(reg, anc, i, b);
                double ih = fmin(b[2], p2) - fmax(b[0], p0); ih = fmax(ih, 0.0);
                double iw = fmin(b[3], p3) - fmax(b[1], p1); iw = fmax(iw, 0.0);
                double inter = ih * iw;
                double aa = (b[2] - b[0]) * (b[3] - b[1]);
                double den = aa + pa; den = den - inter; den = den + 1e-12;
                if (inter / den > 0.4) sbuf[i] = 0.0f;  // kills the pick too
            }
        }
        __syncthreads();
        ln = oi + 1;
    }
    __syncthreads();
    if (tid < MAX_OUT)
        write_row(reg, anc, lnd, tid, (tid < ln) ? s_kept[tid] : -1, out);
}

extern "C" void kernel_launch(void* const* d_in, const int* in_sizes, int n_in,
                              void* d_out, int out_size, void* d_ws, size_t ws_size,
                              hipStream_t stream) {
    const float2* cls = (const float2*)d_in[0];    // (N,2) f32
    const float4* reg = (const float4*)d_in[1];    // (N,4) f32
    const float*  lnd = (const float*)d_in[2];     // (N,10) f32
    const float4* anc = (const float4*)d_in[3];    // (N,4) f32

    uint8_t* w = (uint8_t*)d_ws;
    int*   segcnt  = (int*)w;                  //     0: 672 B (pad to 1024)
    ull*   segkeys = (ull*)(w + 1024);         //  1024: 168*32*8 = 43008 B
    float* sbuf    = (float*)(w + 44032);      // 44032: N*4 B (fallback only)

    k_seg<<<GRID, BLK, 0, stream>>>(cls, segcnt, segkeys);
    k_fused<<<1, BLK, 0, stream>>>(cls, reg, anc, lnd, segcnt, segkeys,
                                   sbuf, (float*)d_out);
}